// Round 12
// baseline (259.156 us; speedup 1.0000x reference)
//
#include <hip/hip_runtime.h>
#include <stdint.h>

// ---------------------------------------------------------------------------
// Bucketed linear attention, round 11: R10 +
//   - fp32->bf16 conversion of x FUSED into gemm<2>'s A-staging (register
//     staged: 8 early dwordx4 loads, cvt + 4 ds_write_b128 late, lgkm drain
//     before publish barrier). cvt_all shrinks to weights-only (16 MB).
//   Ledger (EPI=2): per tile issue A0..A7,Bk0x2,Bk1x2; gates:
//     mid-tile  vmcnt(12)  -> prev tile's B-k1 landed (k1 readable)
//     late-tile vmcnt(4)   -> own A loads landed (cvt+ds_write)
//               lgkmcnt(0) -> ds_writes visible ; vmcnt(2) -> B-k0(t+1)
//   ws layout (~177 MB):
//     xb   (unused region, kept for offsets)   @ 0
//     wq   bf16 qkv_w          6,291,456 B @ 33554432
//     wp   bf16 proj_w         2,097,152 B @ 39845888
//     Qf   bf16 [bkt][n][e]   33,554,432 B @ 41943040
//     Kt   bf16 [bkt][d][n]   33,554,432 B @ 75497472   (exp'd; AT reuses)
//     Vt   bf16 [bkt][e][n]   33,554,432 B @ 109051904
//     ctxb bf16 [bkt][e][d]   33,554,432 B @ 142606336  (excl-scanned)
//     ksum f32  [bkt][d]       1,048,576 B @ 176160768  (in-place excl scan)
// ---------------------------------------------------------------------------

typedef unsigned short u16;
typedef unsigned int u32;
typedef u16   u16x4  __attribute__((ext_vector_type(4)));
typedef u16   u16x8  __attribute__((ext_vector_type(8)));
typedef float f32x4  __attribute__((ext_vector_type(4)));
typedef float float4v __attribute__((ext_vector_type(4)));
typedef __bf16 bf16x8 __attribute__((ext_vector_type(8)));

__device__ __forceinline__ u16 f2bf(float f) {
  return __builtin_bit_cast(u16, (__bf16)f);
}
__device__ __forceinline__ float bf2f(u16 h) {
  return (float)__builtin_bit_cast(__bf16, h);
}

__device__ __forceinline__ void stage16(const u16* g, u16* l) {
  __builtin_amdgcn_global_load_lds(
      (const __attribute__((address_space(1))) u32*)g,
      (__attribute__((address_space(3))) u32*)l, 16, 0, 0);
}

// ------------------- fp32 -> bf16 convert (weights only) --------------------
// ranges (u16x4 units): qkv_w 786432 | proj_w 262144
__global__ __launch_bounds__(256) void cvt_w(
    const float* __restrict__ wqf, const float* __restrict__ wpf,
    u16* __restrict__ wq, u16* __restrict__ wp) {
  int i = blockIdx.x * 256 + threadIdx.x;
  const float* in; u16* out; int j;
  if (i < 786432) { in = wqf; out = wq; j = i; }
  else            { in = wpf; out = wp; j = i - 786432; }
  float4v v = reinterpret_cast<const float4v*>(in)[j];
  u16x4 o;
  o.x = f2bf(v.x); o.y = f2bf(v.y); o.z = f2bf(v.z); o.w = f2bf(v.w);
  reinterpret_cast<u16x4*>(out)[j] = o;
}

// ------------------ 256x256 NT bf16 MFMA GEMM (R3 schedule) -----------------
// EPI=0: A bf16 (async stage16 both operands, R3 ledger), float C + bias.
// EPI=2: A = x fp32 (register-staged cvt), fused feature-map epilogue:
//   bn 0-3: softmax_e(q)*e^-0.5 -> Qf | bn 4-7: exp(k)->Kt + ksum | 8-11: v->Vt
template <int EPI>
__global__ __launch_bounds__(512, 2) void gemm256(
    const u16* __restrict__ A,      // [M][K] bf16 (EPI==0)
    const float* __restrict__ Xf,   // [M][K] fp32 (EPI==2)
    const u16* __restrict__ B,      // [N][K] bf16
    const float* __restrict__ bias, // [N] (EPI==0)
    float* __restrict__ Cf,         // (EPI==0)
    u16* __restrict__ Qf, u16* __restrict__ Kt, u16* __restrict__ Vt,
    float* __restrict__ ksum,
    int N, int K, int NT) {         // NT = K/64
  __shared__ u16 As[2][2][256][32];
  __shared__ u16 Bs[2][2][256][32];
  const int tid = threadIdx.x, lane = tid & 63, wave = tid >> 6;
  const int wm = wave >> 2, wn = wave & 3;
  const int l15 = lane & 15, l4 = lane >> 4;
  const int ntn = N >> 8;
  const int cpx = gridDim.x >> 3;
  const int bid = (blockIdx.x & 7) * cpx + (blockIdx.x >> 3);
  const int bm = bid / ntn, bn = bid % ntn;

  const int srow = tid >> 2;
  const int gsl8 = ((tid & 3) ^ ((tid >> 3) & 3)) * 8;
  const u16* Ag = A ? A + (size_t)(bm * 256 + srow) * K + gsl8 : nullptr;
  const float* Xg = Xf ? Xf + (size_t)(bm * 256 + srow) * K + gsl8 : nullptr;
  const u16* Bg = B + (size_t)(bn * 256 + srow) * K + gsl8;
  const size_t rj = (size_t)128 * K;
  const int slotr = (l4 ^ ((l15 >> 1) & 3)) * 8;

  f32x4 acc[8][4] = {};
  bf16x8 a0, a1, a2, a3, a4, a5, a6, a7, b0, b1, b2, b3;
  float4v p0, p1, p2, p3, p4, p5, p6, p7;

#define STGA(buf, kh, kt)                                          \
  { const u16* g_ = Ag + (kt) + (kh) * 32;                         \
    stage16(g_,      &As[buf][kh][wave * 16][0]);                  \
    stage16(g_ + rj, &As[buf][kh][128 + wave * 16][0]); }
#define STGB(buf, kh, kt)                                          \
  { const u16* g_ = Bg + (kt) + (kh) * 32;                         \
    stage16(g_,      &Bs[buf][kh][wave * 16][0]);                  \
    stage16(g_ + rj, &Bs[buf][kh][128 + wave * 16][0]); }

// A fp32 loads: rows srow, srow+128; 8 floats each = 2 float4
#define AFLD(kh, kt, q0, q1, q2, q3)                               \
  { const float* g0 = Xg + (kt) + (kh) * 32;                       \
    q0 = *(const float4v*)(g0); q1 = *(const float4v*)(g0 + 4);    \
    const float* g1 = g0 + rj;                                     \
    q2 = *(const float4v*)(g1); q3 = *(const float4v*)(g1 + 4); }
#define AWR(buf, kh, q0, q1, q2, q3)                               \
  { u16x8 w;                                                       \
    w[0] = f2bf(q0.x); w[1] = f2bf(q0.y); w[2] = f2bf(q0.z);       \
    w[3] = f2bf(q0.w); w[4] = f2bf(q1.x); w[5] = f2bf(q1.y);       \
    w[6] = f2bf(q1.z); w[7] = f2bf(q1.w);                          \
    *(u16x8*)(&As[buf][kh][srow][(tid & 3) * 8]) = w;              \
    u16x8 w2;                                                      \
    w2[0] = f2bf(q2.x); w2[1] = f2bf(q2.y); w2[2] = f2bf(q2.z);    \
    w2[3] = f2bf(q2.w); w2[4] = f2bf(q3.x); w2[5] = f2bf(q3.y);    \
    w2[6] = f2bf(q3.z); w2[7] = f2bf(q3.w);                        \
    *(u16x8*)(&As[buf][kh][128 + srow][(tid & 3) * 8]) = w2; }

#define LDA(r0_, r1_, r2_, r3_, kk, mh)                                  \
  { const u16* p_ = &As[cur][kk][wm * 128 + (mh) * 64 + l15][0] + slotr; \
    r0_ = *(const bf16x8*)(p_);                                          \
    r1_ = *(const bf16x8*)(p_ + 512);                                    \
    r2_ = *(const bf16x8*)(p_ + 1024);                                   \
    r3_ = *(const bf16x8*)(p_ + 1536); }

#define LDB(kk)                                                    \
  { const u16* p_ = &Bs[cur][kk][wn * 64 + l15][0] + slotr;        \
    b0 = *(const bf16x8*)(p_);                                     \
    b1 = *(const bf16x8*)(p_ + 512);                               \
    b2 = *(const bf16x8*)(p_ + 1024);                              \
    b3 = *(const bf16x8*)(p_ + 1536); }

#define MM(x, y, z) z = __builtin_amdgcn_mfma_f32_16x16x32_bf16(x, y, z, 0, 0, 0)
#define MFMA16(mb, x0, x1, x2, x3)                                 \
  __builtin_amdgcn_s_setprio(1);                                   \
  MM(x0, b0, acc[(mb) + 0][0]); MM(x0, b1, acc[(mb) + 0][1]);      \
  MM(x0, b2, acc[(mb) + 0][2]); MM(x0, b3, acc[(mb) + 0][3]);      \
  MM(x1, b0, acc[(mb) + 1][0]); MM(x1, b1, acc[(mb) + 1][1]);      \
  MM(x1, b2, acc[(mb) + 1][2]); MM(x1, b3, acc[(mb) + 1][3]);      \
  MM(x2, b0, acc[(mb) + 2][0]); MM(x2, b1, acc[(mb) + 2][1]);      \
  MM(x2, b2, acc[(mb) + 2][2]); MM(x2, b3, acc[(mb) + 2][3]);      \
  MM(x3, b0, acc[(mb) + 3][0]); MM(x3, b1, acc[(mb) + 3][1]);      \
  MM(x3, b2, acc[(mb) + 3][2]); MM(x3, b3, acc[(mb) + 3][3]);      \
  __builtin_amdgcn_s_setprio(0);

#define BARF()                                                     \
  { asm volatile("" ::: "memory");                                 \
    __builtin_amdgcn_s_barrier();                                  \
    asm volatile("" ::: "memory"); }

  // prologue
  if constexpr (EPI == 2) {
    AFLD(0, 0, p0, p1, p2, p3) AFLD(1, 0, p4, p5, p6, p7)
    STGB(0, 0, 0) STGB(0, 1, 0)
    asm volatile("s_waitcnt vmcnt(4)" ::: "memory");
    AWR(0, 0, p0, p1, p2, p3) AWR(0, 1, p4, p5, p6, p7)
    asm volatile("s_waitcnt vmcnt(0) lgkmcnt(0)" ::: "memory");
  } else {
    STGA(0, 0, 0) STGB(0, 0, 0) STGA(0, 1, 0) STGB(0, 1, 0)
    asm volatile("s_waitcnt vmcnt(0)" ::: "memory");
  }
  __builtin_amdgcn_s_barrier();
  asm volatile("" ::: "memory");

  for (int t = 0; t < NT; ++t) {
    const int cur = t & 1, nxt = cur ^ 1;
    const int ktn = (t + 1) << 6;
    const bool pre = (t + 1 < NT);
    if constexpr (EPI == 2) {
      LDB(0)
      LDA(a0, a1, a2, a3, 0, 0)
      LDA(a4, a5, a6, a7, 0, 1)
      if (pre) {
        AFLD(0, ktn, p0, p1, p2, p3) AFLD(1, ktn, p4, p5, p6, p7)
        STGB(nxt, 0, ktn) STGB(nxt, 1, ktn)
      }
      MFMA16(0, a0, a1, a2, a3)
      MFMA16(4, a4, a5, a6, a7)
      // mid gate: prev tile's B-k1 (oldest 2) landed -> k1 readable
      if (pre) { asm volatile("s_waitcnt vmcnt(12)" ::: "memory"); }
      else     { asm volatile("s_waitcnt vmcnt(0)" ::: "memory"); }
      BARF()
      LDB(1)
      LDA(a0, a1, a2, a3, 1, 0)
      LDA(a4, a5, a6, a7, 1, 1)
      MFMA16(0, a0, a1, a2, a3)
      MFMA16(4, a4, a5, a6, a7)
      if (pre) {
        asm volatile("s_waitcnt vmcnt(4)" ::: "memory");  // A loads landed
        AWR(nxt, 0, p0, p1, p2, p3) AWR(nxt, 1, p4, p5, p6, p7)
        asm volatile("s_waitcnt vmcnt(2) lgkmcnt(0)" ::: "memory");
        BARF()
      }
    } else {
      LDB(0)
      LDA(a0, a1, a2, a3, 0, 0)
      LDA(a4, a5, a6, a7, 0, 1)
      if (pre) STGA(nxt, 0, ktn)
      MFMA16(0, a0, a1, a2, a3)
      if (pre) STGB(nxt, 0, ktn)
      MFMA16(4, a4, a5, a6, a7)
      if (pre) { asm volatile("s_waitcnt vmcnt(4)" ::: "memory"); }
      else     { asm volatile("s_waitcnt vmcnt(0)" ::: "memory"); }
      BARF()
      LDB(1)
      LDA(a0, a1, a2, a3, 1, 0)
      LDA(a4, a5, a6, a7, 1, 1)
      if (pre) STGA(nxt, 1, ktn)
      MFMA16(0, a0, a1, a2, a3)
      if (pre) STGB(nxt, 1, ktn)
      MFMA16(4, a4, a5, a6, a7)
      if (pre) { asm volatile("s_waitcnt vmcnt(4)" ::: "memory"); }
      BARF()
    }
  }
#undef STGA
#undef STGB
#undef AFLD
#undef AWR
#undef LDA
#undef LDB
#undef MM
#undef MFMA16
#undef BARF

  // epilogue: D row=(lane>>4)*4+reg, col=lane&15
  const int row0 = bm * 256 + wm * 128 + l4 * 4;
  const int col0 = bn * 256 + wn * 64 + l15;
  if constexpr (EPI == 0) {
    float bv[4];
#pragma unroll
    for (int ni = 0; ni < 4; ++ni) bv[ni] = bias[col0 + ni * 16];
#pragma unroll
    for (int mi = 0; mi < 8; ++mi)
#pragma unroll
      for (int i = 0; i < 4; ++i) {
        size_t r = (size_t)(row0 + mi * 16 + i) * N;
#pragma unroll
        for (int ni = 0; ni < 4; ++ni)
          Cf[r + col0 + ni * 16] = acc[mi][ni][i] + bv[ni];
      }
  } else {
    const int i3 = bn >> 2;                  // 0=q, 1=k, 2=v
    const int h  = ((bn & 3) << 2) + wn;     // global head 0..15
    if (i3 == 0) {
#pragma unroll
      for (int mi = 0; mi < 8; ++mi)
#pragma unroll
        for (int i = 0; i < 4; ++i) {
          const int row = row0 + mi * 16 + i;
          const int bb = row >> 12, uu = (row >> 6) & 63, nn = row & 63;
          u16* op = Qf + ((size_t)((bb * 16 + h) * 64 + uu)) * 4096
                        + nn * 64 + l15;
          float v0 = acc[mi][0][i], v1 = acc[mi][1][i];
          float v2 = acc[mi][2][i], v3 = acc[mi][3][i];
          float mx = fmaxf(fmaxf(v0, v1), fmaxf(v2, v3));
          mx = fmaxf(mx, __shfl_xor(mx, 1));
          mx = fmaxf(mx, __shfl_xor(mx, 2));
          mx = fmaxf(mx, __shfl_xor(mx, 4));
          mx = fmaxf(mx, __shfl_xor(mx, 8));
          float e0 = __expf(v0 - mx), e1 = __expf(v1 - mx);
          float e2 = __expf(v2 - mx), e3 = __expf(v3 - mx);
          float s = e0 + e1 + e2 + e3;
          s += __shfl_xor(s, 1); s += __shfl_xor(s, 2);
          s += __shfl_xor(s, 4); s += __shfl_xor(s, 8);
          float inv = 0.125f / s;  // e^-0.5 = 1/8
          op[0]  = f2bf(e0 * inv); op[16] = f2bf(e1 * inv);
          op[32] = f2bf(e2 * inv); op[48] = f2bf(e3 * inv);
        }
    } else if (i3 == 1) {
      float sk0[4] = {0.f, 0.f, 0.f, 0.f};
      float sk1[4] = {0.f, 0.f, 0.f, 0.f};
#pragma unroll
      for (int mi = 0; mi < 8; ++mi) {
        const int row = row0 + mi * 16;
        const int bb = row >> 12, uu = (row >> 6) & 63, nn = row & 63;
        u16* op = Kt + ((size_t)((bb * 16 + h) * 64 + uu)) * 4096 + nn;
#pragma unroll
        for (int ni = 0; ni < 4; ++ni) {
          float e0 = __expf(acc[mi][ni][0]);
          float e1 = __expf(acc[mi][ni][1]);
          float e2 = __expf(acc[mi][ni][2]);
          float e3 = __expf(acc[mi][ni][3]);
          u16x4 o;
          o.x = f2bf(e0); o.y = f2bf(e1); o.z = f2bf(e2); o.w = f2bf(e3);
          *reinterpret_cast<u16x4*>(op + (ni * 16 + l15) * 64) = o;
          if (mi < 4) sk0[ni] += e0 + e1 + e2 + e3;
          else        sk1[ni] += e0 + e1 + e2 + e3;
        }
      }
#pragma unroll
      for (int ni = 0; ni < 4; ++ni) {
        sk0[ni] += __shfl_xor(sk0[ni], 16); sk0[ni] += __shfl_xor(sk0[ni], 32);
        sk1[ni] += __shfl_xor(sk1[ni], 16); sk1[ni] += __shfl_xor(sk1[ni], 32);
      }
      if (lane < 16) {
        const int nb0 = bm * 256 + wm * 128;
        const size_t bkt0 = (size_t)(((nb0 >> 12) * 16 + h) * 64 + ((nb0 >> 6) & 63));
#pragma unroll
        for (int ni = 0; ni < 4; ++ni) {
          ksum[bkt0 * 64 + ni * 16 + l15]       = sk0[ni];
          ksum[(bkt0 + 1) * 64 + ni * 16 + l15] = sk1[ni];
        }
      }
    } else {
#pragma unroll
      for (int mi = 0; mi < 8; ++mi) {
        const int row = row0 + mi * 16;
        const int bb = row >> 12, uu = (row >> 6) & 63, nn = row & 63;
        u16* op = Vt + ((size_t)((bb * 16 + h) * 64 + uu)) * 4096 + nn;
#pragma unroll
        for (int ni = 0; ni < 4; ++ni) {
          u16x4 o;
          o.x = f2bf(acc[mi][ni][0]); o.y = f2bf(acc[mi][ni][1]);
          o.z = f2bf(acc[mi][ni][2]); o.w = f2bf(acc[mi][ni][3]);
          *reinterpret_cast<u16x4*>(op + (ni * 16 + l15) * 64) = o;
        }
      }
    }
  }
}

// ------------- scanctx2 v2: fused K^TV + exclusive scan, 2 buckets/iter ----
__global__ __launch_bounds__(256) void scanctx2(
    const u16* __restrict__ Kt,  // [bkt][d][n] bf16 (exp'd)
    const u16* __restrict__ Vt,  // [bkt][e][n] bf16
    u16* __restrict__ ctxb) {    // [bkt][e][d] bf16 (excl-scanned out)
  const int bh = blockIdx.x >> 2, ec = blockIdx.x & 3;
  const int tid = threadIdx.x, lane = tid & 63, wave = tid >> 6;
  const int l15 = lane & 15, l4 = lane >> 4;
  __shared__ u16 KtL[2][2][64][72];  // [buf][bkt parity][d][n]
  __shared__ u16 VtL[2][2][16][72];

  const size_t bbase = (size_t)bh * 64 * 4096;
  const int kr0 = tid >> 3, ks = (tid & 7) * 8;
  const int kr1 = 32 + kr0;
  const bool dov = tid < 128;
  const int vr = tid >> 3, vs = (tid & 7) * 8;

  f32x4 acc = {0.f, 0.f, 0.f, 0.f};
  u16x8 ka0, ka1, kb0, kb1, va = {}, vb = {};

#define GLD(u_, kx0, kx1, vx)                                          \
  { const size_t nb = bbase + (size_t)(u_) * 4096;                     \
    kx0 = *reinterpret_cast<const u16x8*>(Kt + nb + kr0 * 64 + ks);    \
    kx1 = *reinterpret_cast<const u16x8*>(Kt + nb + kr1 * 64 + ks);    \
    if (dov) vx = *reinterpret_cast<const u16x8*>(                     \
        Vt + nb + (ec * 16 + vr) * 64 + vs); }
#define LWR(buf, j, kx0, kx1, vx)                                      \
  { *reinterpret_cast<u16x8*>(&KtL[buf][j][kr0][ks]) = kx0;            \
    *reinterpret_cast<u16x8*>(&KtL[buf][j][kr1][ks]) = kx1;            \
    if (dov) *reinterpret_cast<u16x8*>(&VtL[buf][j][vr][vs]) = vx; }
#define ACC(buf, j)                                                    \
  _Pragma("unroll")                                                    \
  for (int kk = 0; kk < 2; ++kk) {                                     \
    bf16x8 av = *reinterpret_cast<const bf16x8*>(                      \
        &VtL[buf][j][l15][kk * 32 + l4 * 8]);                          \
    bf16x8 bk = *reinterpret_cast<const bf16x8*>(                      \
        &KtL[buf][j][wave * 16 + l15][kk * 32 + l4 * 8]);              \
    acc = __builtin_amdgcn_mfma_f32_16x16x32_bf16(av, bk, acc, 0, 0, 0); }

  GLD(0, ka0, ka1, va) GLD(1, kb0, kb1, vb)
  LWR(0, 0, ka0, ka1, va) LWR(0, 1, kb0, kb1, vb)
  __syncthreads();

  for (int u = 0; u < 64; u += 2) {
    const int cur = (u >> 1) & 1, nxt = cur ^ 1;
    const bool pre = (u + 2 < 64);
    if (pre) { GLD(u + 2, ka0, ka1, va) GLD(u + 3, kb0, kb1, vb) }
    u16* cb0 = ctxb + bbase + (size_t)u * 4096 + wave * 16 + l15;
#pragma unroll
    for (int i = 0; i < 4; ++i) cb0[(ec * 16 + l4 * 4 + i) * 64] = f2bf(acc[i]);
    ACC(cur, 0)
    u16* cb1 = cb0 + 4096;
#pragma unroll
    for (int i = 0; i < 4; ++i) cb1[(ec * 16 + l4 * 4 + i) * 64] = f2bf(acc[i]);
    ACC(cur, 1)
    if (pre) { LWR(nxt, 0, ka0, ka1, va) LWR(nxt, 1, kb0, kb1, vb) }
    __syncthreads();
  }
#undef GLD
#undef LWR
#undef ACC
}

// ---------------- scanK: in-place exclusive cumsum of ksum over u -----------
__global__ __launch_bounds__(64) void scanK(float* __restrict__ ksum) {
  const int bh = blockIdx.x;
  float* p = ksum + (size_t)bh * 4096 + threadIdx.x;
  float run = 0.f;
#define LK(i) p[(size_t)(i) * 64]
  float c0 = LK(0), c1 = LK(1), c2 = LK(2), c3 = LK(3);
  for (int u = 0; u < 64; u += 4) {
    const int i4 = u + 4 < 64 ? u + 4 : 63, i5 = u + 5 < 64 ? u + 5 : 63;
    const int i6 = u + 6 < 64 ? u + 6 : 63, i7 = u + 7 < 64 ? u + 7 : 63;
    float n0 = LK(i4), n1 = LK(i5), n2 = LK(i6), n3 = LK(i7);
    LK(u) = run;     run += c0;
    LK(u + 1) = run; run += c1;
    LK(u + 2) = run; run += c2;
    LK(u + 3) = run; run += c3;
    c0 = n0; c1 = n1; c2 = n2; c3 = n3;
  }
#undef LK
}

// -------- apply v2: attn = (q @ ctx_excl) * Dinv -> AT (fused D-dot) --------
__global__ __launch_bounds__(256) void apply(
    const u16* __restrict__ Q, const u16* __restrict__ ctxc,
    const float* __restrict__ kcum, u16* __restrict__ AT) {
  const int bid = blockIdx.x;
  const int u = bid & 63, bh = bid >> 6, b = bh >> 4, h = bh & 15;
  const int tid = threadIdx.x, lane = tid & 63, wave = tid >> 6;
  const int l15 = lane & 15, l4 = lane >> 4;
  __shared__ float kc[64];

  const size_t base = (size_t)bid * 4096;
  if (tid < 64) kc[tid] = kcum[(size_t)bid * 64 + tid];
  __syncthreads();

  bf16x8 aq[2];
  float dpart = 0.f;
#pragma unroll
  for (int kk = 0; kk < 2; ++kk) {
    aq[kk] = *reinterpret_cast<const bf16x8*>(
        Q + base + (wave * 16 + l15) * 64 + kk * 32 + l4 * 8);
    const float* kcp = &kc[kk * 32 + l4 * 8];
#pragma unroll
    for (int j = 0; j < 8; ++j) dpart += (float)aq[kk][j] * kcp[j];
  }
  dpart += __shfl_xor(dpart, 16);
  dpart += __shfl_xor(dpart, 32);
  const float dinv_self = 1.f / fmaxf(dpart, 1e-3f);
  float dv[4];
#pragma unroll
  for (int i = 0; i < 4; ++i) dv[i] = __shfl(dinv_self, l4 * 4 + i);

  f32x4 acc[4] = {};
  const u16* Cu = ctxc + base;
#pragma unroll
  for (int kk = 0; kk < 2; ++kk)
#pragma unroll
    for (int ni = 0; ni < 4; ++ni) {
      bf16x8 bc = *reinterpret_cast<const bf16x8*>(
          Cu + (ni * 16 + l15) * 64 + kk * 32 + l4 * 8);
      acc[ni] = __builtin_amdgcn_mfma_f32_16x16x32_bf16(aq[kk], bc, acc[ni], 0, 0, 0);
    }
  const size_t orow = ((size_t)b * 4096 + u * 64 + wave * 16 + l4 * 4) * 1024 + h * 64;
#pragma unroll
  for (int i = 0; i < 4; ++i) {
#pragma unroll
    for (int ni = 0; ni < 4; ++ni)
      AT[orow + (size_t)i * 1024 + ni * 16 + l15] = f2bf(acc[ni][i] * dv[i]);
  }
}

// ----------------------------------------------------------------------------
extern "C" void kernel_launch(void* const* d_in, const int* in_sizes, int n_in,
                              void* d_out, int out_size, void* d_ws, size_t ws_size,
                              hipStream_t stream) {
  (void)in_sizes; (void)n_in; (void)out_size; (void)ws_size;
  const float* x      = (const float*)d_in[0];
  const float* qkv_w  = (const float*)d_in[1];
  const float* proj_w = (const float*)d_in[2];
  const float* proj_b = (const float*)d_in[3];
  float* out = (float*)d_out;

  char* ws = (char*)d_ws;
  u16* wq    = (u16*)(ws + 33554432);
  u16* wp    = (u16*)(ws + 39845888);
  u16* Qf    = (u16*)(ws + 41943040);
  u16* Kt    = (u16*)(ws + 75497472);
  u16* Vt    = (u16*)(ws + 109051904);
  u16* ctxb  = (u16*)(ws + 142606336);
  float* ksum = (float*)(ws + 176160768);
  u16* AT    = Kt;  // Kt is dead after scanctx2; apply writes AT over it

  cvt_w<<<dim3(4096), dim3(256), 0, stream>>>(qkv_w, proj_w, wq, wp);

  gemm256<2><<<dim3(64 * 12), dim3(512), 0, stream>>>(
      nullptr, x, wq, nullptr, nullptr, Qf, Kt, Vt, ksum, 3072, 1024, 16);
  scanK<<<dim3(64), dim3(64), 0, stream>>>(ksum);
  scanctx2<<<dim3(256), dim3(256), 0, stream>>>(Kt, Vt, ctxb);
  apply<<<dim3(4096), dim3(256), 0, stream>>>(Qf, ctxb, ksum, AT);
  gemm256<0><<<dim3(64 * 4), dim3(512), 0, stream>>>(
      AT, nullptr, wp, proj_b, out, nullptr, nullptr, nullptr, nullptr,
      1024, 1024, 16);
}

// Round 13
// 235.712 us; speedup vs baseline: 1.0995x; 1.0995x over previous
//
#include <hip/hip_runtime.h>
#include <stdint.h>

// ---------------------------------------------------------------------------
// Bucketed linear attention, round 12: exact R10 core (best measured) +
// scanK folded into scanctx2 (ksum exclusive scan rides the serial-u loop
// in ec==0 blocks' wave 0). 5 launches.
//   ws layout (~177 MB):
//     xb   bf16 x             33,554,432 B @ 0
//     wq   bf16 qkv_w          6,291,456 B @ 33554432
//     wp   bf16 proj_w         2,097,152 B @ 39845888
//     Qf   bf16 [bkt][n][e]   33,554,432 B @ 41943040
//     Kt   bf16 [bkt][d][n]   33,554,432 B @ 75497472   (exp'd; AT reuses)
//     Vt   bf16 [bkt][e][n]   33,554,432 B @ 109051904
//     ctxb bf16 [bkt][e][d]   33,554,432 B @ 142606336  (excl-scanned)
//     ksum f32  [bkt][d]       1,048,576 B @ 176160768  (in-place excl scan)
// ---------------------------------------------------------------------------

typedef unsigned short u16;
typedef unsigned int u32;
typedef u16   u16x4  __attribute__((ext_vector_type(4)));
typedef u16   u16x8  __attribute__((ext_vector_type(8)));
typedef float f32x4  __attribute__((ext_vector_type(4)));
typedef float float4v __attribute__((ext_vector_type(4)));
typedef __bf16 bf16x8 __attribute__((ext_vector_type(8)));

__device__ __forceinline__ u16 f2bf(float f) {
  return __builtin_bit_cast(u16, (__bf16)f);
}
__device__ __forceinline__ float bf2f(u16 h) {
  return (float)__builtin_bit_cast(__bf16, h);
}

__device__ __forceinline__ void stage16(const u16* g, u16* l) {
  __builtin_amdgcn_global_load_lds(
      (const __attribute__((address_space(1))) u32*)g,
      (__attribute__((address_space(3))) u32*)l, 16, 0, 0);
}

// ------------------- fp32 -> bf16 convert (all 3 inputs) --------------------
__global__ __launch_bounds__(256) void cvt_all(
    const float* __restrict__ x, const float* __restrict__ wqf,
    const float* __restrict__ wpf, u16* __restrict__ xb,
    u16* __restrict__ wq, u16* __restrict__ wp) {
  int i = blockIdx.x * 256 + threadIdx.x;
  const float* in; u16* out; int j;
  if (i < 4194304)      { in = x;   out = xb; j = i; }
  else if (i < 4980736) { in = wqf; out = wq; j = i - 4194304; }
  else                  { in = wpf; out = wp; j = i - 4980736; }
  float4v v = reinterpret_cast<const float4v*>(in)[j];
  u16x4 o;
  o.x = f2bf(v.x); o.y = f2bf(v.y); o.z = f2bf(v.z); o.w = f2bf(v.w);
  reinterpret_cast<u16x4*>(out)[j] = o;
}

// ------------------ 256x256 NT bf16 MFMA GEMM (R3 schedule) -----------------
// EPI=0: float C + bias (proj). EPI=2: fused feature maps ->
//   bn 0-3: softmax_e(q)*e^-0.5 -> Qf[bkt][n][e]
//   bn 4-7: exp(k) -> Kt[bkt][d][n] (u16x4) + ksum[bkt][d] (f32 partials)
//   bn 8-11: v     -> Vt[bkt][e][n] (u16x4)
template <int EPI>
__global__ __launch_bounds__(512, 2) void gemm256(
    const u16* __restrict__ A,      // [M][K] bf16
    const u16* __restrict__ B,      // [N][K] bf16
    const float* __restrict__ bias, // [N] (EPI==0)
    float* __restrict__ Cf,         // (EPI==0)
    u16* __restrict__ Qf, u16* __restrict__ Kt, u16* __restrict__ Vt,
    float* __restrict__ ksum,
    int N, int K, int NT) {         // NT = K/64
  __shared__ u16 As[2][2][256][32];
  __shared__ u16 Bs[2][2][256][32];
  const int tid = threadIdx.x, lane = tid & 63, wave = tid >> 6;
  const int wm = wave >> 2, wn = wave & 3;
  const int l15 = lane & 15, l4 = lane >> 4;
  const int ntn = N >> 8;
  const int cpx = gridDim.x >> 3;
  const int bid = (blockIdx.x & 7) * cpx + (blockIdx.x >> 3);
  const int bm = bid / ntn, bn = bid % ntn;

  const int srow = tid >> 2;
  const int gsl8 = ((tid & 3) ^ ((tid >> 3) & 3)) * 8;
  const u16* Ag = A + (size_t)(bm * 256 + srow) * K + gsl8;
  const u16* Bg = B + (size_t)(bn * 256 + srow) * K + gsl8;
  const size_t rj = (size_t)128 * K;
  const int slotr = (l4 ^ ((l15 >> 1) & 3)) * 8;

  f32x4 acc[8][4] = {};
  bf16x8 a0, a1, a2, a3, a4, a5, a6, a7, b0, b1, b2, b3;

#define STG(P, buf, kh, kt)                                        \
  { const u16* g_ = P##g + (kt) + (kh) * 32;                       \
    stage16(g_,      &P##s[buf][kh][wave * 16][0]);                \
    stage16(g_ + rj, &P##s[buf][kh][128 + wave * 16][0]); }

#define LDA(r0_, r1_, r2_, r3_, kk, mh)                                  \
  { const u16* p_ = &As[cur][kk][wm * 128 + (mh) * 64 + l15][0] + slotr; \
    r0_ = *(const bf16x8*)(p_);                                          \
    r1_ = *(const bf16x8*)(p_ + 512);                                    \
    r2_ = *(const bf16x8*)(p_ + 1024);                                   \
    r3_ = *(const bf16x8*)(p_ + 1536); }

#define LDB(kk)                                                    \
  { const u16* p_ = &Bs[cur][kk][wn * 64 + l15][0] + slotr;        \
    b0 = *(const bf16x8*)(p_);                                     \
    b1 = *(const bf16x8*)(p_ + 512);                               \
    b2 = *(const bf16x8*)(p_ + 1024);                              \
    b3 = *(const bf16x8*)(p_ + 1536); }

#define MM(x, y, z) z = __builtin_amdgcn_mfma_f32_16x16x32_bf16(x, y, z, 0, 0, 0)
#define MFMA16(mb, x0, x1, x2, x3)                                 \
  __builtin_amdgcn_s_setprio(1);                                   \
  MM(x0, b0, acc[(mb) + 0][0]); MM(x0, b1, acc[(mb) + 0][1]);      \
  MM(x0, b2, acc[(mb) + 0][2]); MM(x0, b3, acc[(mb) + 0][3]);      \
  MM(x1, b0, acc[(mb) + 1][0]); MM(x1, b1, acc[(mb) + 1][1]);      \
  MM(x1, b2, acc[(mb) + 1][2]); MM(x1, b3, acc[(mb) + 1][3]);      \
  MM(x2, b0, acc[(mb) + 2][0]); MM(x2, b1, acc[(mb) + 2][1]);      \
  MM(x2, b2, acc[(mb) + 2][2]); MM(x2, b3, acc[(mb) + 2][3]);      \
  MM(x3, b0, acc[(mb) + 3][0]); MM(x3, b1, acc[(mb) + 3][1]);      \
  MM(x3, b2, acc[(mb) + 3][2]); MM(x3, b3, acc[(mb) + 3][3]);      \
  __builtin_amdgcn_s_setprio(0);

#define BARF()                                                     \
  { asm volatile("" ::: "memory");                                 \
    __builtin_amdgcn_s_barrier();                                  \
    asm volatile("" ::: "memory"); }

  STG(A, 0, 0, 0) STG(B, 0, 0, 0) STG(A, 0, 1, 0) STG(B, 0, 1, 0)
  asm volatile("s_waitcnt vmcnt(0)" ::: "memory");
  __builtin_amdgcn_s_barrier();
  asm volatile("" ::: "memory");

  for (int t = 0; t < NT; ++t) {
    const int cur = t & 1, nxt = cur ^ 1;
    const int ktn = (t + 1) << 6;
    const bool pre = (t + 1 < NT);
    LDB(0)
    LDA(a0, a1, a2, a3, 0, 0)
    LDA(a4, a5, a6, a7, 0, 1)
    if (pre) STG(A, nxt, 0, ktn)
    MFMA16(0, a0, a1, a2, a3)
    if (pre) STG(B, nxt, 0, ktn)
    MFMA16(4, a4, a5, a6, a7)
    if (pre) { asm volatile("s_waitcnt vmcnt(4)" ::: "memory"); }
    else     { asm volatile("s_waitcnt vmcnt(0)" ::: "memory"); }
    BARF()
    LDB(1)
    LDA(a0, a1, a2, a3, 1, 0)
    LDA(a4, a5, a6, a7, 1, 1)
    if (pre) STG(A, nxt, 1, ktn)
    MFMA16(0, a0, a1, a2, a3)
    if (pre) STG(B, nxt, 1, ktn)
    MFMA16(4, a4, a5, a6, a7)
    if (pre) { asm volatile("s_waitcnt vmcnt(4)" ::: "memory"); }
    BARF()
  }
#undef STG
#undef LDA
#undef LDB
#undef MM
#undef MFMA16
#undef BARF

  // epilogue: D row=(lane>>4)*4+reg, col=lane&15
  const int row0 = bm * 256 + wm * 128 + l4 * 4;
  const int col0 = bn * 256 + wn * 64 + l15;
  if constexpr (EPI == 0) {
    float bv[4];
#pragma unroll
    for (int ni = 0; ni < 4; ++ni) bv[ni] = bias[col0 + ni * 16];
#pragma unroll
    for (int mi = 0; mi < 8; ++mi)
#pragma unroll
      for (int i = 0; i < 4; ++i) {
        size_t r = (size_t)(row0 + mi * 16 + i) * N;
#pragma unroll
        for (int ni = 0; ni < 4; ++ni)
          Cf[r + col0 + ni * 16] = acc[mi][ni][i] + bv[ni];
      }
  } else {
    const int i3 = bn >> 2;                  // 0=q, 1=k, 2=v
    const int h  = ((bn & 3) << 2) + wn;     // global head 0..15
    if (i3 == 0) {
#pragma unroll
      for (int mi = 0; mi < 8; ++mi)
#pragma unroll
        for (int i = 0; i < 4; ++i) {
          const int row = row0 + mi * 16 + i;
          const int bb = row >> 12, uu = (row >> 6) & 63, nn = row & 63;
          u16* op = Qf + ((size_t)((bb * 16 + h) * 64 + uu)) * 4096
                        + nn * 64 + l15;
          float v0 = acc[mi][0][i], v1 = acc[mi][1][i];
          float v2 = acc[mi][2][i], v3 = acc[mi][3][i];
          float mx = fmaxf(fmaxf(v0, v1), fmaxf(v2, v3));
          mx = fmaxf(mx, __shfl_xor(mx, 1));
          mx = fmaxf(mx, __shfl_xor(mx, 2));
          mx = fmaxf(mx, __shfl_xor(mx, 4));
          mx = fmaxf(mx, __shfl_xor(mx, 8));
          float e0 = __expf(v0 - mx), e1 = __expf(v1 - mx);
          float e2 = __expf(v2 - mx), e3 = __expf(v3 - mx);
          float s = e0 + e1 + e2 + e3;
          s += __shfl_xor(s, 1); s += __shfl_xor(s, 2);
          s += __shfl_xor(s, 4); s += __shfl_xor(s, 8);
          float inv = 0.125f / s;  // e^-0.5 = 1/8
          op[0]  = f2bf(e0 * inv); op[16] = f2bf(e1 * inv);
          op[32] = f2bf(e2 * inv); op[48] = f2bf(e3 * inv);
        }
    } else if (i3 == 1) {
      float sk0[4] = {0.f, 0.f, 0.f, 0.f};
      float sk1[4] = {0.f, 0.f, 0.f, 0.f};
#pragma unroll
      for (int mi = 0; mi < 8; ++mi) {
        const int row = row0 + mi * 16;
        const int bb = row >> 12, uu = (row >> 6) & 63, nn = row & 63;
        u16* op = Kt + ((size_t)((bb * 16 + h) * 64 + uu)) * 4096 + nn;
#pragma unroll
        for (int ni = 0; ni < 4; ++ni) {
          float e0 = __expf(acc[mi][ni][0]);
          float e1 = __expf(acc[mi][ni][1]);
          float e2 = __expf(acc[mi][ni][2]);
          float e3 = __expf(acc[mi][ni][3]);
          u16x4 o;
          o.x = f2bf(e0); o.y = f2bf(e1); o.z = f2bf(e2); o.w = f2bf(e3);
          *reinterpret_cast<u16x4*>(op + (ni * 16 + l15) * 64) = o;
          if (mi < 4) sk0[ni] += e0 + e1 + e2 + e3;
          else        sk1[ni] += e0 + e1 + e2 + e3;
        }
      }
#pragma unroll
      for (int ni = 0; ni < 4; ++ni) {
        sk0[ni] += __shfl_xor(sk0[ni], 16); sk0[ni] += __shfl_xor(sk0[ni], 32);
        sk1[ni] += __shfl_xor(sk1[ni], 16); sk1[ni] += __shfl_xor(sk1[ni], 32);
      }
      if (lane < 16) {
        const int nb0 = bm * 256 + wm * 128;
        const size_t bkt0 = (size_t)(((nb0 >> 12) * 16 + h) * 64 + ((nb0 >> 6) & 63));
#pragma unroll
        for (int ni = 0; ni < 4; ++ni) {
          ksum[bkt0 * 64 + ni * 16 + l15]       = sk0[ni];
          ksum[(bkt0 + 1) * 64 + ni * 16 + l15] = sk1[ni];
        }
      }
    } else {
#pragma unroll
      for (int mi = 0; mi < 8; ++mi) {
        const int row = row0 + mi * 16;
        const int bb = row >> 12, uu = (row >> 6) & 63, nn = row & 63;
        u16* op = Vt + ((size_t)((bb * 16 + h) * 64 + uu)) * 4096 + nn;
#pragma unroll
        for (int ni = 0; ni < 4; ++ni) {
          u16x4 o;
          o.x = f2bf(acc[mi][ni][0]); o.y = f2bf(acc[mi][ni][1]);
          o.z = f2bf(acc[mi][ni][2]); o.w = f2bf(acc[mi][ni][3]);
          *reinterpret_cast<u16x4*>(op + (ni * 16 + l15) * 64) = o;
        }
      }
    }
  }
}

// ---- scanctx2 v3: fused K^TV + exclusive ctx scan + ksum exclusive scan ----
// Block = (bh, ec): 16 e-rows, all 64 d. MFMA accumulator IS the running
// fp32 cumsum. 2 buckets per barrier-iteration; loads one iteration ahead.
// ec==0 blocks' wave 0 additionally performs the ksum exclusive scan
// (in-place, prefetch-before-overwrite), replacing the scanK kernel.
__global__ __launch_bounds__(256) void scanctx2(
    const u16* __restrict__ Kt,  // [bkt][d][n] bf16 (exp'd)
    const u16* __restrict__ Vt,  // [bkt][e][n] bf16
    u16* __restrict__ ctxb,      // [bkt][e][d] bf16 (excl-scanned out)
    float* __restrict__ ksum) {  // [bkt][d] f32 (raw in, exclusive out)
  const int bh = blockIdx.x >> 2, ec = blockIdx.x & 3;
  const int tid = threadIdx.x, lane = tid & 63, wave = tid >> 6;
  const int l15 = lane & 15, l4 = lane >> 4;
  __shared__ u16 KtL[2][2][64][72];  // [buf][bkt parity][d][n]
  __shared__ u16 VtL[2][2][16][72];

  const size_t bbase = (size_t)bh * 64 * 4096;
  const int kr0 = tid >> 3, ks = (tid & 7) * 8;
  const int kr1 = 32 + kr0;
  const bool dov = tid < 128;
  const int vr = tid >> 3, vs = (tid & 7) * 8;
  const bool dok = (ec == 0) && (tid < 64);
  float* kp = dok ? (ksum + (size_t)bh * 4096 + tid) : nullptr;

  f32x4 acc = {0.f, 0.f, 0.f, 0.f};
  u16x8 ka0, ka1, kb0, kb1, va = {}, vb = {};
  float kc0 = 0.f, kc1 = 0.f, kn0 = 0.f, kn1 = 0.f, krun = 0.f;

#define GLD(u_, kx0, kx1, vx)                                          \
  { const size_t nb = bbase + (size_t)(u_) * 4096;                     \
    kx0 = *reinterpret_cast<const u16x8*>(Kt + nb + kr0 * 64 + ks);    \
    kx1 = *reinterpret_cast<const u16x8*>(Kt + nb + kr1 * 64 + ks);    \
    if (dov) vx = *reinterpret_cast<const u16x8*>(                     \
        Vt + nb + (ec * 16 + vr) * 64 + vs); }
#define LWR(buf, j, kx0, kx1, vx)                                      \
  { *reinterpret_cast<u16x8*>(&KtL[buf][j][kr0][ks]) = kx0;            \
    *reinterpret_cast<u16x8*>(&KtL[buf][j][kr1][ks]) = kx1;            \
    if (dov) *reinterpret_cast<u16x8*>(&VtL[buf][j][vr][vs]) = vx; }
#define ACC(buf, j)                                                    \
  _Pragma("unroll")                                                    \
  for (int kk = 0; kk < 2; ++kk) {                                     \
    bf16x8 av = *reinterpret_cast<const bf16x8*>(                      \
        &VtL[buf][j][l15][kk * 32 + l4 * 8]);                          \
    bf16x8 bk = *reinterpret_cast<const bf16x8*>(                      \
        &KtL[buf][j][wave * 16 + l15][kk * 32 + l4 * 8]);              \
    acc = __builtin_amdgcn_mfma_f32_16x16x32_bf16(av, bk, acc, 0, 0, 0); }

  GLD(0, ka0, ka1, va) GLD(1, kb0, kb1, vb)
  if (dok) { kc0 = kp[0]; kc1 = kp[64]; }
  LWR(0, 0, ka0, ka1, va) LWR(0, 1, kb0, kb1, vb)
  __syncthreads();

  for (int u = 0; u < 64; u += 2) {
    const int cur = (u >> 1) & 1, nxt = cur ^ 1;
    const bool pre = (u + 2 < 64);
    if (pre) {
      GLD(u + 2, ka0, ka1, va) GLD(u + 3, kb0, kb1, vb)
      if (dok) { kn0 = kp[(size_t)(u + 2) * 64]; kn1 = kp[(size_t)(u + 3) * 64]; }
    }
    if (dok) {
      kp[(size_t)u * 64] = krun;       krun += kc0;
      kp[(size_t)(u + 1) * 64] = krun; krun += kc1;
      kc0 = kn0; kc1 = kn1;
    }
    u16* cb0 = ctxb + bbase + (size_t)u * 4096 + wave * 16 + l15;
#pragma unroll
    for (int i = 0; i < 4; ++i) cb0[(ec * 16 + l4 * 4 + i) * 64] = f2bf(acc[i]);
    ACC(cur, 0)
    u16* cb1 = cb0 + 4096;
#pragma unroll
    for (int i = 0; i < 4; ++i) cb1[(ec * 16 + l4 * 4 + i) * 64] = f2bf(acc[i]);
    ACC(cur, 1)
    if (pre) { LWR(nxt, 0, ka0, ka1, va) LWR(nxt, 1, kb0, kb1, vb) }
    __syncthreads();
  }
#undef GLD
#undef LWR
#undef ACC
}

// -------- apply v2: attn = (q @ ctx_excl) * Dinv -> AT (fused D-dot) --------
__global__ __launch_bounds__(256) void apply(
    const u16* __restrict__ Q, const u16* __restrict__ ctxc,
    const float* __restrict__ kcum, u16* __restrict__ AT) {
  const int bid = blockIdx.x;
  const int u = bid & 63, bh = bid >> 6, b = bh >> 4, h = bh & 15;
  const int tid = threadIdx.x, lane = tid & 63, wave = tid >> 6;
  const int l15 = lane & 15, l4 = lane >> 4;
  __shared__ float kc[64];

  const size_t base = (size_t)bid * 4096;
  if (tid < 64) kc[tid] = kcum[(size_t)bid * 64 + tid];
  __syncthreads();

  bf16x8 aq[2];
  float dpart = 0.f;
#pragma unroll
  for (int kk = 0; kk < 2; ++kk) {
    aq[kk] = *reinterpret_cast<const bf16x8*>(
        Q + base + (wave * 16 + l15) * 64 + kk * 32 + l4 * 8);
    const float* kcp = &kc[kk * 32 + l4 * 8];
#pragma unroll
    for (int j = 0; j < 8; ++j) dpart += (float)aq[kk][j] * kcp[j];
  }
  dpart += __shfl_xor(dpart, 16);
  dpart += __shfl_xor(dpart, 32);
  const float dinv_self = 1.f / fmaxf(dpart, 1e-3f);
  float dv[4];
#pragma unroll
  for (int i = 0; i < 4; ++i) dv[i] = __shfl(dinv_self, l4 * 4 + i);

  f32x4 acc[4] = {};
  const u16* Cu = ctxc + base;
#pragma unroll
  for (int kk = 0; kk < 2; ++kk)
#pragma unroll
    for (int ni = 0; ni < 4; ++ni) {
      bf16x8 bc = *reinterpret_cast<const bf16x8*>(
          Cu + (ni * 16 + l15) * 64 + kk * 32 + l4 * 8);
      acc[ni] = __builtin_amdgcn_mfma_f32_16x16x32_bf16(aq[kk], bc, acc[ni], 0, 0, 0);
    }
  const size_t orow = ((size_t)b * 4096 + u * 64 + wave * 16 + l4 * 4) * 1024 + h * 64;
#pragma unroll
  for (int i = 0; i < 4; ++i) {
#pragma unroll
    for (int ni = 0; ni < 4; ++ni)
      AT[orow + (size_t)i * 1024 + ni * 16 + l15] = f2bf(acc[ni][i] * dv[i]);
  }
}

// ----------------------------------------------------------------------------
extern "C" void kernel_launch(void* const* d_in, const int* in_sizes, int n_in,
                              void* d_out, int out_size, void* d_ws, size_t ws_size,
                              hipStream_t stream) {
  (void)in_sizes; (void)n_in; (void)out_size; (void)ws_size;
  const float* x      = (const float*)d_in[0];
  const float* qkv_w  = (const float*)d_in[1];
  const float* proj_w = (const float*)d_in[2];
  const float* proj_b = (const float*)d_in[3];
  float* out = (float*)d_out;

  char* ws = (char*)d_ws;
  u16* xb    = (u16*)(ws);
  u16* wq    = (u16*)(ws + 33554432);
  u16* wp    = (u16*)(ws + 39845888);
  u16* Qf    = (u16*)(ws + 41943040);
  u16* Kt    = (u16*)(ws + 75497472);
  u16* Vt    = (u16*)(ws + 109051904);
  u16* ctxb  = (u16*)(ws + 142606336);
  float* ksum = (float*)(ws + 176160768);
  u16* AT    = Kt;  // Kt is dead after scanctx2; apply writes AT over it

  cvt_all<<<dim3(20480), dim3(256), 0, stream>>>(x, qkv_w, proj_w, xb, wq, wp);

  gemm256<2><<<dim3(64 * 12), dim3(512), 0, stream>>>(
      xb, wq, nullptr, nullptr, Qf, Kt, Vt, ksum, 3072, 1024, 16);
  scanctx2<<<dim3(256), dim3(256), 0, stream>>>(Kt, Vt, ctxb, ksum);
  apply<<<dim3(4096), dim3(256), 0, stream>>>(Qf, ctxb, ksum, AT);
  gemm256<0><<<dim3(64 * 4), dim3(512), 0, stream>>>(
      AT, wp, proj_b, out, nullptr, nullptr, nullptr, nullptr, 1024, 1024, 16);
}